// Round 16
// baseline (379.388 us; speedup 1.0000x reference)
//
#include <hip/hip_runtime.h>
#include <hip/hip_bf16.h>
#include <math.h>

#define N_NODES 20000
#define N_EDGES 320000
#define IN_CH   128
#define HEADS   8
#define CPH     128
#define HCH     1024
#define NG      64
#define ETOT    (N_EDGES + N_NODES)
#define NCVT    768
#define NROWT   157            // ceil(20000/128)
#define GRID_P2 (NROWT * 8)    // 1256, divisible by 8
#define PL      ((size_t)N_NODES * 128)   // elements per head-plane

typedef __attribute__((ext_vector_type(8))) short s8v;
typedef __attribute__((ext_vector_type(4))) float f4v;
typedef __attribute__((ext_vector_type(8))) float f8v;
typedef __attribute__((ext_vector_type(4))) unsigned short u16x4;
typedef __attribute__((ext_vector_type(8))) unsigned short u16x8;

// ---- fp32 -> bf16 split helpers (RNE) ----
__device__ __forceinline__ unsigned short bf16_rne(float f) {
    unsigned u = __float_as_uint(f);
    unsigned r = u + 0x7fffu + ((u >> 16) & 1u);
    return (unsigned short)(r >> 16);
}
__device__ __forceinline__ float bf16_to_f(unsigned short h) {
    return __uint_as_float((unsigned)h << 16);
}

// ---- zero deg + pooled ----
__global__ void init_kernel(int* __restrict__ deg, float* __restrict__ pooled) {
    int i = blockIdx.x * blockDim.x + threadIdx.x;
    if (i < N_NODES) deg[i] = 0;
    if (i < NG * CPH) pooled[i] = 0.0f;
}

// ---- fp32 -> (hi,lo) bf16 planes + edge histogram + wcomb (merged) ----
__global__ void cvt_all(const float* __restrict__ x,  const float* __restrict__ Wl,
                        const float* __restrict__ Wr, const float* __restrict__ Wlin,
                        unsigned short* __restrict__ xhi,  unsigned short* __restrict__ xlo,
                        unsigned short* __restrict__ wlhi, unsigned short* __restrict__ wllo,
                        unsigned short* __restrict__ wrhi, unsigned short* __restrict__ wrlo,
                        unsigned short* __restrict__ wnhi, unsigned short* __restrict__ wnlo,
                        const int* __restrict__ ei, int* __restrict__ deg,
                        const float* __restrict__ Wres, const float* __restrict__ bias_conv,
                        const float* __restrict__ blin,
                        unsigned short* __restrict__ wchi, unsigned short* __restrict__ wclo,
                        float* __restrict__ bcomb)
{
    const int t = threadIdx.x;
    if (blockIdx.x < NCVT) {
        const int NX = N_NODES * IN_CH, NW = HCH * IN_CH;
        const int TOT4 = (NX + 3 * NW) >> 2;
        const int stride = NCVT * 256;
        for (int q = blockIdx.x * 256 + t; q < TOT4; q += stride) {
            int i = q << 2;
            const float* s; unsigned short *hi, *lo; int k;
            if (i < NX)               { s = x;    hi = xhi;  lo = xlo;  k = i; }
            else if (i < NX + NW)     { s = Wl;   hi = wlhi; lo = wllo; k = i - NX; }
            else if (i < NX + 2 * NW) { s = Wr;   hi = wrhi; lo = wrlo; k = i - NX - NW; }
            else                      { s = Wlin; hi = wnhi; lo = wnlo; k = i - NX - 2 * NW; }
            f4v f = *(const f4v*)&s[k];
            u16x4 h, l;
            #pragma unroll
            for (int e = 0; e < 4; ++e) {
                unsigned short hh = bf16_rne(f[e]);
                h[e] = hh;
                l[e] = bf16_rne(f[e] - bf16_to_f(hh));
            }
            *(u16x4*)&hi[k] = h;
            *(u16x4*)&lo[k] = l;
        }
        for (int e = blockIdx.x * 256 + t; e < ETOT; e += stride) {
            int dst = (e < N_EDGES) ? ei[N_EDGES + e] : (e - N_EDGES);
            atomicAdd(&deg[dst], 1);
        }
    } else if (t < 128) {
        // Wcomb = Wlin @ Wres, bcomb = blin + Wlin @ bias_conv
        const int j = blockIdx.x - NCVT;    // 0..127
        float s = 0.0f, pb = 0.0f;
        for (int m = 0; m < HCH; ++m) {
            float wl = Wlin[j * HCH + m];
            s  += wl * Wres[m * IN_CH + t];
            pb += wl * bias_conv[m];
        }
        unsigned short h = bf16_rne(s);
        wchi[j * IN_CH + t] = h;
        wclo[j * IN_CH + t] = bf16_rne(s - bf16_to_f(h));
        if (t == 0) bcomb[j] = blin[j] + pb;
    }
}

// ---- merged projection GEMM: both WL and WR per block (2 passes) ----
// 1256 blocks (row-tile x head); per-block fixed costs amortized over 2x work.
__global__ __launch_bounds__(256) void proj_gemm(
    const unsigned short* __restrict__ Ahi,
    const unsigned short* __restrict__ WLhi, const unsigned short* __restrict__ WLlo,
    const unsigned short* __restrict__ WRhi, const unsigned short* __restrict__ WRlo,
    const float* __restrict__ bl, const float* __restrict__ br,
    const float* __restrict__ att,
    unsigned short* __restrict__ xl_h, unsigned short* __restrict__ xr_h,
    float* __restrict__ dl, float* __restrict__ dr, int M)
{
    __shared__ unsigned short cst[128][136];
    const int id  = blockIdx.x;
    const int nat = (id & 7) * (GRID_P2 / 8) + (id >> 3);   // XCD-contiguous
    const int bx  = nat >> 3;        // row-tile   0..156
    const int hh  = nat & 7;         // head       0..7
    const int t    = threadIdx.x;
    const int wave = t >> 6, lane = t & 63;
    const int wr = wave >> 1, wc = wave & 1;
    const int l15 = lane & 15, lg = lane >> 4;
    const int m0 = bx * 128 + wr * 64;
    const int col0 = hh * 128;
    const int koff = lg * 8;
    const int K = IN_CH;

    int rowA[4], colB[4];
    #pragma unroll
    for (int i = 0; i < 4; ++i) { int r = m0 + i * 16 + l15; rowA[i] = r < M ? r : M - 1; }
    #pragma unroll
    for (int j = 0; j < 4; ++j) colB[j] = col0 + wc * 64 + j * 16 + l15;

    #pragma unroll
    for (int sel = 0; sel < 2; ++sel) {
        const unsigned short* Whi = sel ? WRhi : WLhi;
        const unsigned short* Wlo = sel ? WRlo : WLlo;
        const float* bias = sel ? br : bl;
        unsigned short* C = sel ? xr_h : xl_h;
        float* D = sel ? dr : dl;

        float bj[4];
        #pragma unroll
        for (int j = 0; j < 4; ++j) bj[j] = bias[colB[j]];

        f4v acc[4][4];
        #pragma unroll
        for (int i = 0; i < 4; ++i)
            #pragma unroll
            for (int j = 0; j < 4; ++j) acc[i][j] = (f4v){0.f, 0.f, 0.f, 0.f};

        for (int k0 = 0; k0 < K; k0 += 32) {
            s8v ah[4], bh[4], blv[4];
            #pragma unroll
            for (int i = 0; i < 4; ++i)
                ah[i] = *(const s8v*)&Ahi[(size_t)rowA[i] * K + k0 + koff];
            #pragma unroll
            for (int j = 0; j < 4; ++j) {
                size_t off = (size_t)colB[j] * K + k0 + koff;
                bh[j]  = *(const s8v*)&Whi[off];
                blv[j] = *(const s8v*)&Wlo[off];
            }
            #pragma unroll
            for (int i = 0; i < 4; ++i)
                #pragma unroll
                for (int j = 0; j < 4; ++j) {
                    acc[i][j] = __builtin_amdgcn_mfma_f32_16x16x32_bf16(ah[i], bh[j],  acc[i][j], 0, 0, 0);
                    acc[i][j] = __builtin_amdgcn_mfma_f32_16x16x32_bf16(ah[i], blv[j], acc[i][j], 0, 0, 0);
                }
        }

        // stage as bf16 (+bias)
        #pragma unroll
        for (int i = 0; i < 4; ++i)
            #pragma unroll
            for (int r = 0; r < 4; ++r) {
                int lr = wr * 64 + i * 16 + lg * 4 + r;
                #pragma unroll
                for (int j = 0; j < 4; ++j)
                    cst[lr][wc * 64 + j * 16 + l15] = bf16_rne(acc[i][j][r] + bj[j]);
            }
        __syncthreads();

        // contiguous plane-major store: 32 KB sequential per pass
        {
            const int c8  = (t & 15) * 8;
            const int r16 = t >> 4;
            #pragma unroll
            for (int it = 0; it < 8; ++it) {
                int lr = it * 16 + r16;
                int row = bx * 128 + lr;
                if (row >= M) continue;
                u16x8 v = *(const u16x8*)&cst[lr][c8];
                *(u16x8*)&C[(size_t)hh * PL + (size_t)row * 128 + c8] = v;
            }
        }

        // att-dot per row (this head)
        {
            const int r2  = t >> 1;            // row 0..127
            const int ch0 = (t & 1) * 64;
            float q = 0.0f;
            #pragma unroll
            for (int c = 0; c < 64; c += 8) {
                u16x8 cv = *(const u16x8*)&cst[r2][ch0 + c];
                f4v a0 = *(const f4v*)&att[hh * 128 + ch0 + c];
                f4v a1 = *(const f4v*)&att[hh * 128 + ch0 + c + 4];
                q = fmaf(a0[0], bf16_to_f(cv[0]), q);
                q = fmaf(a0[1], bf16_to_f(cv[1]), q);
                q = fmaf(a0[2], bf16_to_f(cv[2]), q);
                q = fmaf(a0[3], bf16_to_f(cv[3]), q);
                q = fmaf(a1[0], bf16_to_f(cv[4]), q);
                q = fmaf(a1[1], bf16_to_f(cv[5]), q);
                q = fmaf(a1[2], bf16_to_f(cv[6]), q);
                q = fmaf(a1[3], bf16_to_f(cv[7]), q);
            }
            q += __shfl_xor(q, 1, 64);
            int row = bx * 128 + r2;
            if ((t & 1) == 0 && row < M) D[hh * N_NODES + row] = q;
        }
        __syncthreads();   // cst reused by next sel pass
    }
}

// ---- final GEMM + ELU + fused pooling: 64-row tile, 2 waves ----
__global__ __launch_bounds__(128) void mfma_gemm2(
    const unsigned short* __restrict__ A1h,
    const unsigned short* __restrict__ B1hi, const unsigned short* __restrict__ B1lo, int K1,
    const unsigned short* __restrict__ A2hi, const unsigned short* __restrict__ A2lo,
    const unsigned short* __restrict__ B2hi, const unsigned short* __restrict__ B2lo, int K2,
    const float* __restrict__ bias, const int* __restrict__ batch,
    float* __restrict__ pooled, int M)
{
    __shared__ float cst[64][130];
    __shared__ int batch_s[64];
    const int t    = threadIdx.x;
    const int wc   = t >> 6, lane = t & 63;
    const int l15 = lane & 15, lg = lane >> 4;
    const int m0 = blockIdx.x * 64;
    const int n0 = wc * 64;
    const int koff = lg * 8;

    if (t < 64) {
        int row = m0 + t;
        batch_s[t] = (row < M) ? batch[row] : -1;
    }

    int rowA[4], colB[4];
    #pragma unroll
    for (int i = 0; i < 4; ++i) { int r = m0 + i * 16 + l15; rowA[i] = r < M ? r : M - 1; }
    #pragma unroll
    for (int j = 0; j < 4; ++j) colB[j] = n0 + j * 16 + l15;

    float bj[4];
    #pragma unroll
    for (int j = 0; j < 4; ++j) bj[j] = bias[colB[j]];

    f4v acc[4][4];
    #pragma unroll
    for (int i = 0; i < 4; ++i)
        #pragma unroll
        for (int j = 0; j < 4; ++j) acc[i][j] = (f4v){0.f, 0.f, 0.f, 0.f};

    for (int k0 = 0; k0 < K1; k0 += 32) {
        s8v ah[4], bh[4], blv[4];
        #pragma unroll
        for (int i = 0; i < 4; ++i)
            ah[i] = *(const s8v*)&A1h[(size_t)rowA[i] * K1 + k0 + koff];
        #pragma unroll
        for (int j = 0; j < 4; ++j) {
            size_t off = (size_t)colB[j] * K1 + k0 + koff;
            bh[j]  = *(const s8v*)&B1hi[off];
            blv[j] = *(const s8v*)&B1lo[off];
        }
        #pragma unroll
        for (int i = 0; i < 4; ++i)
            #pragma unroll
            for (int j = 0; j < 4; ++j) {
                acc[i][j] = __builtin_amdgcn_mfma_f32_16x16x32_bf16(ah[i], bh[j],  acc[i][j], 0, 0, 0);
                acc[i][j] = __builtin_amdgcn_mfma_f32_16x16x32_bf16(ah[i], blv[j], acc[i][j], 0, 0, 0);
            }
    }
    for (int k0 = 0; k0 < K2; k0 += 32) {
        s8v ah[4], al[4], bh[4], blv[4];
        #pragma unroll
        for (int i = 0; i < 4; ++i) {
            size_t off = (size_t)rowA[i] * K2 + k0 + koff;
            ah[i] = *(const s8v*)&A2hi[off];
            al[i] = *(const s8v*)&A2lo[off];
        }
        #pragma unroll
        for (int j = 0; j < 4; ++j) {
            size_t off = (size_t)colB[j] * K2 + k0 + koff;
            bh[j]  = *(const s8v*)&B2hi[off];
            blv[j] = *(const s8v*)&B2lo[off];
        }
        #pragma unroll
        for (int i = 0; i < 4; ++i)
            #pragma unroll
            for (int j = 0; j < 4; ++j) {
                acc[i][j] = __builtin_amdgcn_mfma_f32_16x16x32_bf16(ah[i], bh[j],  acc[i][j], 0, 0, 0);
                acc[i][j] = __builtin_amdgcn_mfma_f32_16x16x32_bf16(ah[i], blv[j], acc[i][j], 0, 0, 0);
                acc[i][j] = __builtin_amdgcn_mfma_f32_16x16x32_bf16(al[i], bh[j],  acc[i][j], 0, 0, 0);
            }
    }

    #pragma unroll
    for (int i = 0; i < 4; ++i)
        #pragma unroll
        for (int r = 0; r < 4; ++r) {
            int lr = i * 16 + lg * 4 + r;
            #pragma unroll
            for (int j = 0; j < 4; ++j) {
                float v = acc[i][j][r] + bj[j];
                v = v > 0.0f ? v : expm1f(v);   // ELU
                cst[lr][n0 + j * 16 + l15] = v;
            }
        }
    __syncthreads();

    const int col = t;
    float run = 0.0f;
    int cur_g = -2;
    #pragma unroll 4
    for (int r = 0; r < 64; ++r) {
        int g = batch_s[r];
        if (g != cur_g) {
            if (cur_g >= 0) atomicAdd(&pooled[cur_g * CPH + col], run);
            run = 0.0f; cur_g = g;
        }
        if (g >= 0) run += cst[r][col];
    }
    if (cur_g >= 0) atomicAdd(&pooled[cur_g * CPH + col], run);
}

// ---- CSR build: single-block scan, 4 elems/thread ----
__global__ __launch_bounds__(256) void scan_kernel(
    const int* __restrict__ deg, int* __restrict__ rowptr, int* __restrict__ wof)
{
    __shared__ int wsum[4];
    __shared__ int carry_s;
    const int t = threadIdx.x, wave = t >> 6, lane = t & 63;
    if (t == 0) { carry_s = 0; rowptr[0] = 0; }
    __syncthreads();
    for (int base = 0; base < N_NODES; base += 1024) {
        int idx = base + t * 4;
        int d[4], p[4];
        #pragma unroll
        for (int k = 0; k < 4; ++k)
            d[k] = (idx + k < N_NODES) ? deg[idx + k] : 0;
        p[0] = d[0]; p[1] = p[0] + d[1]; p[2] = p[1] + d[2]; p[3] = p[2] + d[3];
        int v = p[3];
        #pragma unroll
        for (int off = 1; off < 64; off <<= 1) {
            int u = __shfl_up(v, off, 64);
            if (lane >= off) v += u;
        }
        if (lane == 63) wsum[wave] = v;
        __syncthreads();
        int woff = carry_s;
        #pragma unroll
        for (int w = 0; w < 4; ++w) if (w < wave) woff += wsum[w];
        int tbase = woff + v - p[3];
        #pragma unroll
        for (int k = 0; k < 4; ++k) {
            if (idx + k < N_NODES) {
                rowptr[idx + k + 1] = tbase + p[k];
                wof[idx + k] = tbase + p[k] - d[k];
            }
        }
        __syncthreads();
        if (t == 255) carry_s = woff + v;
        __syncthreads();
    }
}

// ---- CSR build: scatter edge src ids ----
__global__ void scatter_kernel(const int* __restrict__ ei, int* __restrict__ wof,
                               int* __restrict__ csr_src)
{
    for (int e = blockIdx.x * blockDim.x + threadIdx.x; e < ETOT;
         e += gridDim.x * blockDim.x) {
        int src, dst;
        if (e < N_EDGES) { src = ei[e]; dst = ei[N_EDGES + e]; }
        else             { src = dst = e - N_EDGES; }
        int p = atomicAdd(&wof[dst], 1);
        csr_src[p] = src;
    }
}

// ---- fused logits + online softmax + aggregation (plane-major inputs) ----
__global__ __launch_bounds__(256) void agg_fused(
    const unsigned short* __restrict__ xl_h, const unsigned short* __restrict__ xr_h,
    const float* __restrict__ att,
    const float* __restrict__ dl, const float* __restrict__ dr,
    const int* __restrict__ rowptr, const int* __restrict__ csr_src,
    unsigned short* __restrict__ agg_h, int dst0)
{
    __shared__ float lds_m[128], lds_s[128];
    __shared__ float lds_acc[8][128];
    const int dst = blockIdx.x + dst0;
    const int t = threadIdx.x;       // 0..255
    const int grp = t >> 7;          // edge-group 0/1
    const int u = t & 127;           // channel-slice index
    const int h = u >> 4;            // head, 16 lanes each
    const int c16 = (u & 15) * 8;    // within-plane column offset
    const size_t pbase = (size_t)h * PL + c16;
    const int beg = rowptr[dst], end = rowptr[dst + 1];

    const u16x8 bh8 = *(const u16x8*)&xr_h[pbase + (size_t)dst * 128];
    f8v b;
    #pragma unroll
    for (int e = 0; e < 8; ++e) b[e] = bf16_to_f(bh8[e]);
    f8v w04;
    {
        f4v a0 = *(const f4v*)&att[u * 8];
        f4v a1 = *(const f4v*)&att[u * 8 + 4];
        #pragma unroll
        for (int e = 0; e < 4; ++e) { w04[e] = 0.4f * a0[e]; w04[e + 4] = 0.4f * a1[e]; }
    }
    const float pb = 0.6f * dr[h * N_NODES + dst];

    float m = -__builtin_inff(), s = 0.0f;
    f8v acc = {0.f, 0.f, 0.f, 0.f, 0.f, 0.f, 0.f, 0.f};

    int j = beg + grp * 2;
    for (; j + 1 < end; j += 4) {
        const int s0 = csr_src[j], s1 = csr_src[j + 1];
        const u16x8 vh0 = *(const u16x8*)&xl_h[pbase + (size_t)s0 * 128];
        const u16x8 vh1 = *(const u16x8*)&xl_h[pbase + (size_t)s1 * 128];
        const float d0 = dl[h * N_NODES + s0], d1 = dl[h * N_NODES + s1];
        f8v v0, v1;
        #pragma unroll
        for (int e = 0; e < 8; ++e) { v0[e] = bf16_to_f(vh0[e]); v1[e] = bf16_to_f(vh1[e]); }

        float q0 = w04[0] * __builtin_fabsf(v0[0] + b[0]);
        float q1 = w04[0] * __builtin_fabsf(v1[0] + b[0]);
        #pragma unroll
        for (int e = 1; e < 8; ++e) {
            q0 = fmaf(w04[e], __builtin_fabsf(v0[e] + b[e]), q0);
            q1 = fmaf(w04[e], __builtin_fabsf(v1[e] + b[e]), q1);
        }
        #pragma unroll
        for (int off = 8; off; off >>= 1) {
            q0 += __shfl_xor(q0, off, 16);
            q1 += __shfl_xor(q1, off, 16);
        }
        const float p0 = fmaf(0.6f, d0, q0) + pb;
        const float p1 = fmaf(0.6f, d1, q1) + pb;

        const float mx = fmaxf(p0, p1);
        if (mx > m) {
            float scale = __expf(m - mx);   // first pair: exp(-inf)=0
            float e0 = __expf(p0 - mx), e1 = __expf(p1 - mx);
            s = s * scale + e0 + e1;
            acc = acc * scale + v0 * e0 + v1 * e1;
            m = mx;
        } else {
            float e0 = __expf(p0 - m), e1 = __expf(p1 - m);
            s += e0 + e1;
            acc += v0 * e0 + v1 * e1;
        }
    }
    if (j < end) {   // group's tail edge
        const int s0 = csr_src[j];
        const u16x8 vh0 = *(const u16x8*)&xl_h[pbase + (size_t)s0 * 128];
        const float d0 = dl[h * N_NODES + s0];
        f8v v0;
        #pragma unroll
        for (int e = 0; e < 8; ++e) v0[e] = bf16_to_f(vh0[e]);
        float q0 = w04[0] * __builtin_fabsf(v0[0] + b[0]);
        #pragma unroll
        for (int e = 1; e < 8; ++e)
            q0 = fmaf(w04[e], __builtin_fabsf(v0[e] + b[e]), q0);
        #pragma unroll
        for (int off = 8; off; off >>= 1) q0 += __shfl_xor(q0, off, 16);
        const float p0 = fmaf(0.6f, d0, q0) + pb;
        if (p0 > m) {
            float scale = __expf(m - p0);
            s = s * scale + 1.0f;
            acc = acc * scale + v0;
            m = p0;
        } else {
            float e0 = __expf(p0 - m);
            s += e0;
            acc += v0 * e0;
        }
    }

    // exact split-softmax merge: group 1 -> LDS, group 0 combines
    if (grp == 1) {
        lds_m[u] = m;
        lds_s[u] = s;
        #pragma unroll
        for (int e = 0; e < 8; ++e) lds_acc[e][u] = acc[e];
    }
    __syncthreads();
    if (grp == 0) {
        const float m1 = lds_m[u], s1 = lds_s[u];
        const float M  = fmaxf(m, m1);          // m (group 0) always finite
        const float c0 = __expf(m - M);
        const float c1 = __expf(m1 - M);        // m1=-inf -> 0
        const float S  = s * c0 + s1 * c1;
        const float inv = 1.0f / (S + 1e-16f);
        u16x8 hv;
        #pragma unroll
        for (int e = 0; e < 8; ++e) {
            float r = (acc[e] * c0 + lds_acc[e][u] * c1) * inv;
            hv[e] = bf16_rne(r);
        }
        *(u16x8*)&agg_h[(size_t)dst * HCH + u * 8] = hv;
    }
}

// ---- MLP head: one block per graph, parallel dot products ----
__global__ __launch_bounds__(128) void head_kernel(
    const float* __restrict__ pooled, const int* __restrict__ batch,
    const float* __restrict__ W1, const float* __restrict__ b1,
    const float* __restrict__ W2, const float* __restrict__ b2,
    const float* __restrict__ W3, const float* __restrict__ b3,
    float* __restrict__ out)
{
    __shared__ float sm_pool[128];
    __shared__ float sm_y1[16];
    __shared__ float sm_y2[32];
    const int g = blockIdx.x;
    const int t = threadIdx.x;

    int lo = 0, hi = N_NODES;
    while (lo < hi) { int mid = (lo + hi) >> 1; if (batch[mid] <  g) lo = mid + 1; else hi = mid; }
    const int s0 = lo;
    hi = N_NODES;
    while (lo < hi) { int mid = (lo + hi) >> 1; if (batch[mid] <= g) lo = mid + 1; else hi = mid; }
    const float inv = 1.0f / fmaxf((float)(lo - s0), 1.0f);

    sm_pool[t] = pooled[g * CPH + t] * inv;
    __syncthreads();

    {
        const int j  = t >> 3;
        const int c0 = (t & 7) * 16;
        float s = 0.0f;
        #pragma unroll
        for (int k = 0; k < 16; k += 4) {
            f4v wv = *(const f4v*)&W1[j * CPH + c0 + k];
            f4v pv = *(const f4v*)&sm_pool[c0 + k];
            s = fmaf(wv[0], pv[0], s); s = fmaf(wv[1], pv[1], s);
            s = fmaf(wv[2], pv[2], s); s = fmaf(wv[3], pv[3], s);
        }
        s += __shfl_xor(s, 1, 8);
        s += __shfl_xor(s, 2, 8);
        s += __shfl_xor(s, 4, 8);
        if ((t & 7) == 0) sm_y1[j] = fmaxf(s + b1[j], 0.0f);
    }
    __syncthreads();

    if (t < 32) {
        float s = b2[t];
        #pragma unroll
        for (int k = 0; k < 16; ++k) s = fmaf(W2[t * 16 + k], sm_y1[k], s);
        sm_y2[t] = fmaxf(s, 0.0f);
    }
    __syncthreads();

    if (t < 5) {
        float s = b3[t];
        #pragma unroll
        for (int k = 0; k < 32; ++k) s = fmaf(W3[t * 32 + k], sm_y2[k], s);
        out[g * 5 + t] = s;
    }
}

extern "C" void kernel_launch(void* const* d_in, const int* in_sizes, int n_in,
                              void* d_out, int out_size, void* d_ws, size_t ws_size,
                              hipStream_t stream)
{
    const float* x         = (const float*)d_in[0];
    const int*   ei        = (const int*)  d_in[1];
    const int*   batch     = (const int*)  d_in[2];
    const float* Wl        = (const float*)d_in[3];
    const float* bl        = (const float*)d_in[4];
    const float* Wr        = (const float*)d_in[5];
    const float* br        = (const float*)d_in[6];
    const float* att       = (const float*)d_in[7];
    const float* Wres      = (const float*)d_in[8];
    const float* bias_conv = (const float*)d_in[9];
    const float* Wlin      = (const float*)d_in[10];
    const float* blin      = (const float*)d_in[11];
    const float* W1        = (const float*)d_in[12];
    const float* b1        = (const float*)d_in[13];
    const float* W2        = (const float*)d_in[14];
    const float* b2        = (const float*)d_in[15];
    const float* W3        = (const float*)d_in[16];
    const float* b3        = (const float*)d_in[17];
    float* out = (float*)d_out;

    // ---- workspace layout (~139 MB) ----
    unsigned short* xl_h  = (unsigned short*)d_ws;              // [8][N][128] u16 41 MB
    unsigned short* xr_h  = xl_h + (size_t)N_NODES * HCH;       // [8][N][128] u16 41 MB
    unsigned short* agg_h = xr_h + (size_t)N_NODES * HCH;       // [N][1024] u16 41 MB
    float* pooled = (float*)(agg_h + (size_t)N_NODES * HCH);    // NG*CPH f
    float* bcomb  = pooled + NG * CPH;                          // 128 f
    float* dl     = bcomb + 128;                                // [8][N] f
    float* dr     = dl + (size_t)N_NODES * 8;                   // [8][N] f
    unsigned short* x_hi  = (unsigned short*)(dr + (size_t)N_NODES * 8);
    unsigned short* x_lo  = x_hi  + (size_t)N_NODES * IN_CH;
    unsigned short* wl_hi = x_lo  + (size_t)N_NODES * IN_CH;
    unsigned short* wl_lo = wl_hi + HCH * IN_CH;
    unsigned short* wr_hi = wl_lo + HCH * IN_CH;
    unsigned short* wr_lo = wr_hi + HCH * IN_CH;
    unsigned short* wn_hi = wr_lo + HCH * IN_CH;
    unsigned short* wn_lo = wn_hi + CPH * HCH;
    unsigned short* wc_hi = wn_lo + CPH * HCH;
    unsigned short* wc_lo = wc_hi + CPH * IN_CH;
    int* deg     = (int*)(wc_lo + CPH * IN_CH);                 // N
    int* rowptr  = deg + N_NODES;                               // N+1
    int* wof     = rowptr + N_NODES + 1;                        // N
    int* csr_src = wof + N_NODES;                               // ETOT

    init_kernel<<<(N_NODES + 255) / 256, 256, 0, stream>>>(deg, pooled);

    cvt_all<<<NCVT + 128, 256, 0, stream>>>(x, Wl, Wr, Wlin,
                                            x_hi, x_lo, wl_hi, wl_lo,
                                            wr_hi, wr_lo, wn_hi, wn_lo,
                                            ei, deg,
                                            Wres, bias_conv, blin,
                                            wc_hi, wc_lo, bcomb);

    proj_gemm<<<GRID_P2, 256, 0, stream>>>(x_hi, wl_hi, wl_lo, wr_hi, wr_lo,
                                           bl, br, att, xl_h, xr_h, dl, dr, N_NODES);

    scan_kernel<<<1, 256, 0, stream>>>(deg, rowptr, wof);
    scatter_kernel<<<1024, 256, 0, stream>>>(ei, wof, csr_src);

    agg_fused<<<N_NODES / 2, 256, 0, stream>>>(xl_h, xr_h, att, dl, dr,
                                               rowptr, csr_src, agg_h, 0);
    agg_fused<<<N_NODES / 2, 256, 0, stream>>>(xl_h, xr_h, att, dl, dr,
                                               rowptr, csr_src, agg_h, N_NODES / 2);

    dim3 g2((N_NODES + 63) / 64, 1);
    mfma_gemm2<<<g2, 128, 0, stream>>>(agg_h, wn_hi, wn_lo, HCH,
                                       x_hi, x_lo, wc_hi, wc_lo, IN_CH,
                                       bcomb, batch, pooled, N_NODES);

    head_kernel<<<NG, 128, 0, stream>>>(pooled, batch, W1, b1, W2, b2, W3, b3, out);
}

// Round 17
// 363.781 us; speedup vs baseline: 1.0429x; 1.0429x over previous
//
#include <hip/hip_runtime.h>
#include <hip/hip_bf16.h>
#include <math.h>

#define N_NODES 20000
#define N_EDGES 320000
#define IN_CH   128
#define HEADS   8
#define CPH     128
#define HCH     1024
#define NG      64
#define ETOT    (N_EDGES + N_NODES)
#define NCVT    768
#define NROWT   157            // ceil(20000/128)
#define GRID_P  (NROWT * 16)   // 2512, divisible by 8
#define PL      ((size_t)N_NODES * 128)   // elements per head-plane

typedef __attribute__((ext_vector_type(8))) short s8v;
typedef __attribute__((ext_vector_type(4))) float f4v;
typedef __attribute__((ext_vector_type(8))) float f8v;
typedef __attribute__((ext_vector_type(4))) unsigned short u16x4;
typedef __attribute__((ext_vector_type(8))) unsigned short u16x8;

// ---- fp32 -> bf16 split helpers (RNE) ----
__device__ __forceinline__ unsigned short bf16_rne(float f) {
    unsigned u = __float_as_uint(f);
    unsigned r = u + 0x7fffu + ((u >> 16) & 1u);
    return (unsigned short)(r >> 16);
}
__device__ __forceinline__ float bf16_to_f(unsigned short h) {
    return __uint_as_float((unsigned)h << 16);
}

// ---- zero deg + pooled ----
__global__ void init_kernel(int* __restrict__ deg, float* __restrict__ pooled) {
    int i = blockIdx.x * blockDim.x + threadIdx.x;
    if (i < N_NODES) deg[i] = 0;
    if (i < NG * CPH) pooled[i] = 0.0f;
}

// ---- fp32 -> (hi,lo) bf16 planes + edge histogram + wcomb (merged) ----
__global__ void cvt_all(const float* __restrict__ x,  const float* __restrict__ Wl,
                        const float* __restrict__ Wr, const float* __restrict__ Wlin,
                        unsigned short* __restrict__ xhi,  unsigned short* __restrict__ xlo,
                        unsigned short* __restrict__ wlhi, unsigned short* __restrict__ wllo,
                        unsigned short* __restrict__ wrhi, unsigned short* __restrict__ wrlo,
                        unsigned short* __restrict__ wnhi, unsigned short* __restrict__ wnlo,
                        const int* __restrict__ ei, int* __restrict__ deg,
                        const float* __restrict__ Wres, const float* __restrict__ bias_conv,
                        const float* __restrict__ blin,
                        unsigned short* __restrict__ wchi, unsigned short* __restrict__ wclo,
                        float* __restrict__ bcomb)
{
    const int t = threadIdx.x;
    if (blockIdx.x < NCVT) {
        const int NX = N_NODES * IN_CH, NW = HCH * IN_CH;
        const int TOT4 = (NX + 3 * NW) >> 2;
        const int stride = NCVT * 256;
        for (int q = blockIdx.x * 256 + t; q < TOT4; q += stride) {
            int i = q << 2;
            const float* s; unsigned short *hi, *lo; int k;
            if (i < NX)               { s = x;    hi = xhi;  lo = xlo;  k = i; }
            else if (i < NX + NW)     { s = Wl;   hi = wlhi; lo = wllo; k = i - NX; }
            else if (i < NX + 2 * NW) { s = Wr;   hi = wrhi; lo = wrlo; k = i - NX - NW; }
            else                      { s = Wlin; hi = wnhi; lo = wnlo; k = i - NX - 2 * NW; }
            f4v f = *(const f4v*)&s[k];
            u16x4 h, l;
            #pragma unroll
            for (int e = 0; e < 4; ++e) {
                unsigned short hh = bf16_rne(f[e]);
                h[e] = hh;
                l[e] = bf16_rne(f[e] - bf16_to_f(hh));
            }
            *(u16x4*)&hi[k] = h;
            *(u16x4*)&lo[k] = l;
        }
        for (int e = blockIdx.x * 256 + t; e < ETOT; e += stride) {
            int dst = (e < N_EDGES) ? ei[N_EDGES + e] : (e - N_EDGES);
            atomicAdd(&deg[dst], 1);
        }
    } else if (t < 128) {
        // Wcomb = Wlin @ Wres, bcomb = blin + Wlin @ bias_conv
        const int j = blockIdx.x - NCVT;    // 0..127
        float s = 0.0f, pb = 0.0f;
        for (int m = 0; m < HCH; ++m) {
            float wl = Wlin[j * HCH + m];
            s  += wl * Wres[m * IN_CH + t];
            pb += wl * bias_conv[m];
        }
        unsigned short h = bf16_rne(s);
        wchi[j * IN_CH + t] = h;
        wclo[j * IN_CH + t] = bf16_rne(s - bf16_to_f(h));
        if (t == 0) bcomb[j] = blin[j] + pb;
    }
}

// ---- merged projection GEMM, plane-major output (R15-proven: 74 us) ----
__global__ __launch_bounds__(256) void proj_gemm(
    const unsigned short* __restrict__ Ahi,
    const unsigned short* __restrict__ WLhi, const unsigned short* __restrict__ WLlo,
    const unsigned short* __restrict__ WRhi, const unsigned short* __restrict__ WRlo,
    const float* __restrict__ bl, const float* __restrict__ br,
    const float* __restrict__ att,
    unsigned short* __restrict__ xl_h, unsigned short* __restrict__ xr_h,
    float* __restrict__ dl, float* __restrict__ dr, int M)
{
    __shared__ unsigned short cst[128][136];
    const int id  = blockIdx.x;
    const int nat = (id & 7) * (GRID_P / 8) + (id >> 3);   // XCD-contiguous
    const int bx  = nat >> 4;        // row-tile   0..156
    const int by  = nat & 15;        // col-block  0..15
    const int t    = threadIdx.x;
    const int wave = t >> 6, lane = t & 63;
    const int wr = wave >> 1, wc = wave & 1;
    const int l15 = lane & 15, lg = lane >> 4;
    const int m0 = bx * 128 + wr * 64;
    const int sel = by >> 3;
    const int hh  = by & 7;
    const int col0 = hh * 128;
    const unsigned short* Whi = sel ? WRhi : WLhi;
    const unsigned short* Wlo = sel ? WRlo : WLlo;
    const float* bias = sel ? br : bl;
    unsigned short* C = sel ? xr_h : xl_h;
    float* D = sel ? dr : dl;
    const int koff = lg * 8;
    const int K = IN_CH;

    int rowA[4], colB[4];
    #pragma unroll
    for (int i = 0; i < 4; ++i) { int r = m0 + i * 16 + l15; rowA[i] = r < M ? r : M - 1; }
    #pragma unroll
    for (int j = 0; j < 4; ++j) colB[j] = col0 + wc * 64 + j * 16 + l15;

    float bj[4];
    #pragma unroll
    for (int j = 0; j < 4; ++j) bj[j] = bias[colB[j]];

    f4v acc[4][4];
    #pragma unroll
    for (int i = 0; i < 4; ++i)
        #pragma unroll
        for (int j = 0; j < 4; ++j) acc[i][j] = (f4v){0.f, 0.f, 0.f, 0.f};

    for (int k0 = 0; k0 < K; k0 += 32) {
        s8v ah[4], bh[4], blv[4];
        #pragma unroll
        for (int i = 0; i < 4; ++i)
            ah[i] = *(const s8v*)&Ahi[(size_t)rowA[i] * K + k0 + koff];
        #pragma unroll
        for (int j = 0; j < 4; ++j) {
            size_t off = (size_t)colB[j] * K + k0 + koff;
            bh[j]  = *(const s8v*)&Whi[off];
            blv[j] = *(const s8v*)&Wlo[off];
        }
        #pragma unroll
        for (int i = 0; i < 4; ++i)
            #pragma unroll
            for (int j = 0; j < 4; ++j) {
                acc[i][j] = __builtin_amdgcn_mfma_f32_16x16x32_bf16(ah[i], bh[j],  acc[i][j], 0, 0, 0);
                acc[i][j] = __builtin_amdgcn_mfma_f32_16x16x32_bf16(ah[i], blv[j], acc[i][j], 0, 0, 0);
            }
    }

    // stage as bf16 (+bias)
    #pragma unroll
    for (int i = 0; i < 4; ++i)
        #pragma unroll
        for (int r = 0; r < 4; ++r) {
            int lr = wr * 64 + i * 16 + lg * 4 + r;
            #pragma unroll
            for (int j = 0; j < 4; ++j)
                cst[lr][wc * 64 + j * 16 + l15] = bf16_rne(acc[i][j][r] + bj[j]);
        }
    __syncthreads();

    // contiguous plane-major store: 32 KB sequential per block
    {
        const int c8  = (t & 15) * 8;
        const int r16 = t >> 4;
        #pragma unroll
        for (int it = 0; it < 8; ++it) {
            int lr = it * 16 + r16;
            int row = bx * 128 + lr;
            if (row >= M) continue;
            u16x8 v = *(const u16x8*)&cst[lr][c8];
            *(u16x8*)&C[(size_t)hh * PL + (size_t)row * 128 + c8] = v;
        }
    }

    // att-dot per row (this head), plane-major dl/dr
    {
        const int r2  = t >> 1;            // row 0..127
        const int ch0 = (t & 1) * 64;
        float q = 0.0f;
        #pragma unroll
        for (int c = 0; c < 64; c += 8) {
            u16x8 cv = *(const u16x8*)&cst[r2][ch0 + c];
            f4v a0 = *(const f4v*)&att[hh * 128 + ch0 + c];
            f4v a1 = *(const f4v*)&att[hh * 128 + ch0 + c + 4];
            q = fmaf(a0[0], bf16_to_f(cv[0]), q);
            q = fmaf(a0[1], bf16_to_f(cv[1]), q);
            q = fmaf(a0[2], bf16_to_f(cv[2]), q);
            q = fmaf(a0[3], bf16_to_f(cv[3]), q);
            q = fmaf(a1[0], bf16_to_f(cv[4]), q);
            q = fmaf(a1[1], bf16_to_f(cv[5]), q);
            q = fmaf(a1[2], bf16_to_f(cv[6]), q);
            q = fmaf(a1[3], bf16_to_f(cv[7]), q);
        }
        q += __shfl_xor(q, 1, 64);
        int row = bx * 128 + r2;
        if ((t & 1) == 0 && row < M) D[hh * N_NODES + row] = q;
    }
}

// ---- final GEMM + ELU + fused pooling: 32-row tile, 2 waves, 625 blocks ----
__global__ __launch_bounds__(128) void mfma_gemm2(
    const unsigned short* __restrict__ A1h,
    const unsigned short* __restrict__ B1hi, const unsigned short* __restrict__ B1lo, int K1,
    const unsigned short* __restrict__ A2hi, const unsigned short* __restrict__ A2lo,
    const unsigned short* __restrict__ B2hi, const unsigned short* __restrict__ B2lo, int K2,
    const float* __restrict__ bias, const int* __restrict__ batch,
    float* __restrict__ pooled, int M)
{
    __shared__ float cst[32][130];
    __shared__ int batch_s[32];
    const int t    = threadIdx.x;
    const int wc   = t >> 6, lane = t & 63;
    const int l15 = lane & 15, lg = lane >> 4;
    const int m0 = blockIdx.x * 32;
    const int n0 = wc * 64;
    const int koff = lg * 8;

    if (t < 32) {
        int row = m0 + t;
        batch_s[t] = (row < M) ? batch[row] : -1;
    }

    int rowA[2], colB[4];
    #pragma unroll
    for (int i = 0; i < 2; ++i) { int r = m0 + i * 16 + l15; rowA[i] = r < M ? r : M - 1; }
    #pragma unroll
    for (int j = 0; j < 4; ++j) colB[j] = n0 + j * 16 + l15;

    float bj[4];
    #pragma unroll
    for (int j = 0; j < 4; ++j) bj[j] = bias[colB[j]];

    f4v acc[2][4];
    #pragma unroll
    for (int i = 0; i < 2; ++i)
        #pragma unroll
        for (int j = 0; j < 4; ++j) acc[i][j] = (f4v){0.f, 0.f, 0.f, 0.f};

    for (int k0 = 0; k0 < K1; k0 += 32) {
        s8v ah[2], bh[4], blv[4];
        #pragma unroll
        for (int i = 0; i < 2; ++i)
            ah[i] = *(const s8v*)&A1h[(size_t)rowA[i] * K1 + k0 + koff];
        #pragma unroll
        for (int j = 0; j < 4; ++j) {
            size_t off = (size_t)colB[j] * K1 + k0 + koff;
            bh[j]  = *(const s8v*)&B1hi[off];
            blv[j] = *(const s8v*)&B1lo[off];
        }
        #pragma unroll
        for (int i = 0; i < 2; ++i)
            #pragma unroll
            for (int j = 0; j < 4; ++j) {
                acc[i][j] = __builtin_amdgcn_mfma_f32_16x16x32_bf16(ah[i], bh[j],  acc[i][j], 0, 0, 0);
                acc[i][j] = __builtin_amdgcn_mfma_f32_16x16x32_bf16(ah[i], blv[j], acc[i][j], 0, 0, 0);
            }
    }
    for (int k0 = 0; k0 < K2; k0 += 32) {
        s8v ah[2], al[2], bh[4], blv[4];
        #pragma unroll
        for (int i = 0; i < 2; ++i) {
            size_t off = (size_t)rowA[i] * K2 + k0 + koff;
            ah[i] = *(const s8v*)&A2hi[off];
            al[i] = *(const s8v*)&A2lo[off];
        }
        #pragma unroll
        for (int j = 0; j < 4; ++j) {
            size_t off = (size_t)colB[j] * K2 + k0 + koff;
            bh[j]  = *(const s8v*)&B2hi[off];
            blv[j] = *(const s8v*)&B2lo[off];
        }
        #pragma unroll
        for (int i = 0; i < 2; ++i)
            #pragma unroll
            for (int j = 0; j < 4; ++j) {
                acc[i][j] = __builtin_amdgcn_mfma_f32_16x16x32_bf16(ah[i], bh[j],  acc[i][j], 0, 0, 0);
                acc[i][j] = __builtin_amdgcn_mfma_f32_16x16x32_bf16(ah[i], blv[j], acc[i][j], 0, 0, 0);
                acc[i][j] = __builtin_amdgcn_mfma_f32_16x16x32_bf16(al[i], bh[j],  acc[i][j], 0, 0, 0);
            }
    }

    #pragma unroll
    for (int i = 0; i < 2; ++i)
        #pragma unroll
        for (int r = 0; r < 4; ++r) {
            int lr = i * 16 + lg * 4 + r;
            #pragma unroll
            for (int j = 0; j < 4; ++j) {
                float v = acc[i][j][r] + bj[j];
                v = v > 0.0f ? v : expm1f(v);   // ELU
                cst[lr][n0 + j * 16 + l15] = v;
            }
        }
    __syncthreads();

    // per-graph segment reduce: thread t owns column t over 32 rows
    const int col = t;
    if (col < 128) {
        float run = 0.0f;
        int cur_g = -2;
        #pragma unroll 4
        for (int r = 0; r < 32; ++r) {
            int g = batch_s[r];
            if (g != cur_g) {
                if (cur_g >= 0) atomicAdd(&pooled[cur_g * CPH + col], run);
                run = 0.0f; cur_g = g;
            }
            if (g >= 0) run += cst[r][col];
        }
        if (cur_g >= 0) atomicAdd(&pooled[cur_g * CPH + col], run);
    }
}

// ---- CSR build: single-block scan, 4 elems/thread ----
__global__ __launch_bounds__(256) void scan_kernel(
    const int* __restrict__ deg, int* __restrict__ rowptr, int* __restrict__ wof)
{
    __shared__ int wsum[4];
    __shared__ int carry_s;
    const int t = threadIdx.x, wave = t >> 6, lane = t & 63;
    if (t == 0) { carry_s = 0; rowptr[0] = 0; }
    __syncthreads();
    for (int base = 0; base < N_NODES; base += 1024) {
        int idx = base + t * 4;
        int d[4], p[4];
        #pragma unroll
        for (int k = 0; k < 4; ++k)
            d[k] = (idx + k < N_NODES) ? deg[idx + k] : 0;
        p[0] = d[0]; p[1] = p[0] + d[1]; p[2] = p[1] + d[2]; p[3] = p[2] + d[3];
        int v = p[3];
        #pragma unroll
        for (int off = 1; off < 64; off <<= 1) {
            int u = __shfl_up(v, off, 64);
            if (lane >= off) v += u;
        }
        if (lane == 63) wsum[wave] = v;
        __syncthreads();
        int woff = carry_s;
        #pragma unroll
        for (int w = 0; w < 4; ++w) if (w < wave) woff += wsum[w];
        int tbase = woff + v - p[3];
        #pragma unroll
        for (int k = 0; k < 4; ++k) {
            if (idx + k < N_NODES) {
                rowptr[idx + k + 1] = tbase + p[k];
                wof[idx + k] = tbase + p[k] - d[k];
            }
        }
        __syncthreads();
        if (t == 255) carry_s = woff + v;
        __syncthreads();
    }
}

// ---- CSR build: scatter edge src ids ----
__global__ void scatter_kernel(const int* __restrict__ ei, int* __restrict__ wof,
                               int* __restrict__ csr_src)
{
    for (int e = blockIdx.x * blockDim.x + threadIdx.x; e < ETOT;
         e += gridDim.x * blockDim.x) {
        int src, dst;
        if (e < N_EDGES) { src = ei[e]; dst = ei[N_EDGES + e]; }
        else             { src = dst = e - N_EDGES; }
        int p = atomicAdd(&wof[dst], 1);
        csr_src[p] = src;
    }
}

// ---- fused logits + online softmax + aggregation (plane-major inputs) ----
__global__ __launch_bounds__(256) void agg_fused(
    const unsigned short* __restrict__ xl_h, const unsigned short* __restrict__ xr_h,
    const float* __restrict__ att,
    const float* __restrict__ dl, const float* __restrict__ dr,
    const int* __restrict__ rowptr, const int* __restrict__ csr_src,
    unsigned short* __restrict__ agg_h)
{
    __shared__ float lds_m[128], lds_s[128];
    __shared__ float lds_acc[8][128];
    const int dst = blockIdx.x;
    const int t = threadIdx.x;       // 0..255
    const int grp = t >> 7;          // edge-group 0/1
    const int u = t & 127;           // channel-slice index
    const int h = u >> 4;            // head, 16 lanes each
    const int c16 = (u & 15) * 8;    // within-plane column offset
    const size_t pbase = (size_t)h * PL + c16;
    const int beg = rowptr[dst], end = rowptr[dst + 1];

    const u16x8 bh8 = *(const u16x8*)&xr_h[pbase + (size_t)dst * 128];
    f8v b;
    #pragma unroll
    for (int e = 0; e < 8; ++e) b[e] = bf16_to_f(bh8[e]);
    f8v w04;
    {
        f4v a0 = *(const f4v*)&att[u * 8];
        f4v a1 = *(const f4v*)&att[u * 8 + 4];
        #pragma unroll
        for (int e = 0; e < 4; ++e) { w04[e] = 0.4f * a0[e]; w04[e + 4] = 0.4f * a1[e]; }
    }
    const float pb = 0.6f * dr[h * N_NODES + dst];

    float m = -__builtin_inff(), s = 0.0f;
    f8v acc = {0.f, 0.f, 0.f, 0.f, 0.f, 0.f, 0.f, 0.f};

    int j = beg + grp * 2;
    for (; j + 1 < end; j += 4) {
        const int s0 = csr_src[j], s1 = csr_src[j + 1];
        const u16x8 vh0 = *(const u16x8*)&xl_h[pbase + (size_t)s0 * 128];
        const u16x8 vh1 = *(const u16x8*)&xl_h[pbase + (size_t)s1 * 128];
        const float d0 = dl[h * N_NODES + s0], d1 = dl[h * N_NODES + s1];
        f8v v0, v1;
        #pragma unroll
        for (int e = 0; e < 8; ++e) { v0[e] = bf16_to_f(vh0[e]); v1[e] = bf16_to_f(vh1[e]); }

        float q0 = w04[0] * __builtin_fabsf(v0[0] + b[0]);
        float q1 = w04[0] * __builtin_fabsf(v1[0] + b[0]);
        #pragma unroll
        for (int e = 1; e < 8; ++e) {
            q0 = fmaf(w04[e], __builtin_fabsf(v0[e] + b[e]), q0);
            q1 = fmaf(w04[e], __builtin_fabsf(v1[e] + b[e]), q1);
        }
        #pragma unroll
        for (int off = 8; off; off >>= 1) {
            q0 += __shfl_xor(q0, off, 16);
            q1 += __shfl_xor(q1, off, 16);
        }
        const float p0 = fmaf(0.6f, d0, q0) + pb;
        const float p1 = fmaf(0.6f, d1, q1) + pb;

        const float mx = fmaxf(p0, p1);
        if (mx > m) {
            float scale = __expf(m - mx);   // first pair: exp(-inf)=0
            float e0 = __expf(p0 - mx), e1 = __expf(p1 - mx);
            s = s * scale + e0 + e1;
            acc = acc * scale + v0 * e0 + v1 * e1;
            m = mx;
        } else {
            float e0 = __expf(p0 - m), e1 = __expf(p1 - m);
            s += e0 + e1;
            acc += v0 * e0 + v1 * e1;
        }
    }
    if (j < end) {   // group's tail edge
        const int s0 = csr_src[j];
        const u16x8 vh0 = *(const u16x8*)&xl_h[pbase + (size_t)s0 * 128];
        const float d0 = dl[h * N_NODES + s0];
        f8v v0;
        #pragma unroll
        for (int e = 0; e < 8; ++e) v0[e] = bf16_to_f(vh0[e]);
        float q0 = w04[0] * __builtin_fabsf(v0[0] + b[0]);
        #pragma unroll
        for (int e = 1; e < 8; ++e)
            q0 = fmaf(w04[e], __builtin_fabsf(v0[e] + b[e]), q0);
        #pragma unroll
        for (int off = 8; off; off >>= 1) q0 += __shfl_xor(q0, off, 16);
        const float p0 = fmaf(0.6f, d0, q0) + pb;
        if (p0 > m) {
            float scale = __expf(m - p0);
            s = s * scale + 1.0f;
            acc = acc * scale + v0;
            m = p0;
        } else {
            float e0 = __expf(p0 - m);
            s += e0;
            acc += v0 * e0;
        }
    }

    // exact split-softmax merge: group 1 -> LDS, group 0 combines
    if (grp == 1) {
        lds_m[u] = m;
        lds_s[u] = s;
        #pragma unroll
        for (int e = 0; e < 8; ++e) lds_acc[e][u] = acc[e];
    }
    __syncthreads();
    if (grp == 0) {
        const float m1 = lds_m[u], s1 = lds_s[u];
        const float M  = fmaxf(m, m1);          // m (group 0) always finite
        const float c0 = __expf(m - M);
        const float c1 = __expf(m1 - M);        // m1=-inf -> 0
        const float S  = s * c0 + s1 * c1;
        const float inv = 1.0f / (S + 1e-16f);
        u16x8 hv;
        #pragma unroll
        for (int e = 0; e < 8; ++e) {
            float r = (acc[e] * c0 + lds_acc[e][u] * c1) * inv;
            hv[e] = bf16_rne(r);
        }
        *(u16x8*)&agg_h[(size_t)dst * HCH + u * 8] = hv;
    }
}

// ---- MLP head: one block per graph, parallel dot products ----
__global__ __launch_bounds__(128) void head_kernel(
    const float* __restrict__ pooled, const int* __restrict__ batch,
    const float* __restrict__ W1, const float* __restrict__ b1,
    const float* __restrict__ W2, const float* __restrict__ b2,
    const float* __restrict__ W3, const float* __restrict__ b3,
    float* __restrict__ out)
{
    __shared__ float sm_pool[128];
    __shared__ float sm_y1[16];
    __shared__ float sm_y2[32];
    const int g = blockIdx.x;
    const int t = threadIdx.x;

    int lo = 0, hi = N_NODES;
    while (lo < hi) { int mid = (lo + hi) >> 1; if (batch[mid] <  g) lo = mid + 1; else hi = mid; }
    const int s0 = lo;
    hi = N_NODES;
    while (lo < hi) { int mid = (lo + hi) >> 1; if (batch[mid] <= g) lo = mid + 1; else hi = mid; }
    const float inv = 1.0f / fmaxf((float)(lo - s0), 1.0f);

    sm_pool[t] = pooled[g * CPH + t] * inv;
    __syncthreads();

    {
        const int j  = t >> 3;
        const int c0 = (t & 7) * 16;
        float s = 0.0f;
        #pragma unroll
        for (int k = 0; k < 16; k += 4) {
            f4v wv = *(const f4v*)&W1[j * CPH + c0 + k];
            f4v pv = *(const f4v*)&sm_pool[c0 + k];
            s = fmaf(wv[0], pv[0], s); s = fmaf(wv[1], pv[1], s);
            s = fmaf(wv[2], pv[2], s); s = fmaf(wv[3], pv[3], s);
        }
        s += __shfl_xor(s, 1, 8);
        s += __shfl_xor(s, 2, 8);
        s += __shfl_xor(s, 4, 8);
        if ((t & 7) == 0) sm_y1[j] = fmaxf(s + b1[j], 0.0f);
    }
    __syncthreads();

    if (t < 32) {
        float s = b2[t];
        #pragma unroll
        for (int k = 0; k < 16; ++k) s = fmaf(W2[t * 16 + k], sm_y1[k], s);
        sm_y2[t] = fmaxf(s, 0.0f);
    }
    __syncthreads();

    if (t < 5) {
        float s = b3[t];
        #pragma unroll
        for (int k = 0; k < 32; ++k) s = fmaf(W3[t * 32 + k], sm_y2[k], s);
        out[g * 5 + t] = s;
    }
}

extern "C" void kernel_launch(void* const* d_in, const int* in_sizes, int n_in,
                              void* d_out, int out_size, void* d_ws, size_t ws_size,
                              hipStream_t stream)
{
    const float* x         = (const float*)d_in[0];
    const int*   ei        = (const int*)  d_in[1];
    const int*   batch     = (const int*)  d_in[2];
    const float* Wl        = (const float*)d_in[3];
    const float* bl        = (const float*)d_in[4];
    const float* Wr        = (const float*)d_in[5];
    const float* br        = (const float*)d_in[6];
    const float* att       = (const float*)d_in[7];
    const float* Wres      = (const float*)d_in[8];
    const float* bias_conv = (const float*)d_in[9];
    const float* Wlin      = (const float*)d_in[10];
    const float* blin      = (const float*)d_in[11];
    const float* W1        = (const float*)d_in[12];
    const float* b1        = (const float*)d_in[13];
    const float* W2        = (const float*)d_in[14];
    const float* b2        = (const float*)d_in[15];
    const float* W3        = (const float*)d_in[16];
    const float* b3        = (const float*)d_in[17];
    float* out = (float*)d_out;

    // ---- workspace layout (~139 MB) ----
    unsigned short* xl_h  = (unsigned short*)d_ws;              // [8][N][128] u16 41 MB
    unsigned short* xr_h  = xl_h + (size_t)N_NODES * HCH;       // [8][N][128] u16 41 MB
    unsigned short* agg_h = xr_h + (size_t)N_NODES * HCH;       // [N][1024] u16 41 MB
    float* pooled = (float*)(agg_h + (size_t)N_NODES * HCH);    // NG*CPH f
    float* bcomb  = pooled + NG * CPH;                          // 128 f
    float* dl     = bcomb + 128;                                // [8][N] f
    float* dr     = dl + (size_t)N_NODES * 8;                   // [8][N] f
    unsigned short* x_hi  = (unsigned short*)(dr + (size_t)N_NODES * 8);
    unsigned short* x_lo  = x_hi  + (size_t)N_NODES * IN_CH;
    unsigned short* wl_hi = x_lo  + (size_t)N_NODES * IN_CH;
    unsigned short* wl_lo = wl_hi + HCH * IN_CH;
    unsigned short* wr_hi = wl_lo + HCH * IN_CH;
    unsigned short* wr_lo = wr_hi + HCH * IN_CH;
    unsigned short* wn_hi = wr_lo + HCH * IN_CH;
    unsigned short* wn_lo = wn_hi + CPH * HCH;
    unsigned short* wc_hi = wn_lo + CPH * HCH;
    unsigned short* wc_lo = wc_hi + CPH * IN_CH;
    int* deg     = (int*)(wc_lo + CPH * IN_CH);                 // N
    int* rowptr  = deg + N_NODES;                               // N+1
    int* wof     = rowptr + N_NODES + 1;                        // N
    int* csr_src = wof + N_NODES;                               // ETOT

    init_kernel<<<(N_NODES + 255) / 256, 256, 0, stream>>>(deg, pooled);

    cvt_all<<<NCVT + 128, 256, 0, stream>>>(x, Wl, Wr, Wlin,
                                            x_hi, x_lo, wl_hi, wl_lo,
                                            wr_hi, wr_lo, wn_hi, wn_lo,
                                            ei, deg,
                                            Wres, bias_conv, blin,
                                            wc_hi, wc_lo, bcomb);

    proj_gemm<<<GRID_P, 256, 0, stream>>>(x_hi, wl_hi, wl_lo, wr_hi, wr_lo,
                                          bl, br, att, xl_h, xr_h, dl, dr, N_NODES);

    scan_kernel<<<1, 256, 0, stream>>>(deg, rowptr, wof);
    scatter_kernel<<<1024, 256, 0, stream>>>(ei, wof, csr_src);

    agg_fused<<<N_NODES, 256, 0, stream>>>(xl_h, xr_h, att, dl, dr,
                                           rowptr, csr_src, agg_h);

    dim3 g2((N_NODES + 31) / 32, 1);
    mfma_gemm2<<<g2, 128, 0, stream>>>(agg_h, wn_hi, wn_lo, HCH,
                                       x_hi, x_lo, wc_hi, wc_lo, IN_CH,
                                       bcomb, batch, pooled, N_NODES);

    head_kernel<<<NG, 128, 0, stream>>>(pooled, batch, W1, b1, W2, b2, W3, b3, out);
}

// Round 18
// 348.597 us; speedup vs baseline: 1.0883x; 1.0436x over previous
//
#include <hip/hip_runtime.h>
#include <hip/hip_bf16.h>
#include <math.h>

#define N_NODES 20000
#define N_EDGES 320000
#define IN_CH   128
#define HEADS   8
#define CPH     128
#define HCH     1024
#define NG      64
#define ETOT    (N_EDGES + N_NODES)
#define NCVT    768
#define NROWT   157            // ceil(20000/128)
#define GRID_P  (NROWT * 16)   // 2512, divisible by 8
#define PL      ((size_t)N_NODES * 128)   // elements per head-plane

typedef __attribute__((ext_vector_type(8))) short s8v;
typedef __attribute__((ext_vector_type(4))) float f4v;
typedef __attribute__((ext_vector_type(8))) float f8v;
typedef __attribute__((ext_vector_type(4))) unsigned short u16x4;
typedef __attribute__((ext_vector_type(8))) unsigned short u16x8;

// ---- fp32 -> bf16 split helpers (RNE) ----
__device__ __forceinline__ unsigned short bf16_rne(float f) {
    unsigned u = __float_as_uint(f);
    unsigned r = u + 0x7fffu + ((u >> 16) & 1u);
    return (unsigned short)(r >> 16);
}
__device__ __forceinline__ float bf16_to_f(unsigned short h) {
    return __uint_as_float((unsigned)h << 16);
}

// ---- zero deg + pooled ----
__global__ void init_kernel(int* __restrict__ deg, float* __restrict__ pooled) {
    int i = blockIdx.x * blockDim.x + threadIdx.x;
    if (i < N_NODES) deg[i] = 0;
    if (i < NG * CPH) pooled[i] = 0.0f;
}

// ---- fp32 -> (hi,lo) bf16 planes + edge histogram + wcomb (merged) ----
__global__ void cvt_all(const float* __restrict__ x,  const float* __restrict__ Wl,
                        const float* __restrict__ Wr, const float* __restrict__ Wlin,
                        unsigned short* __restrict__ xhi,  unsigned short* __restrict__ xlo,
                        unsigned short* __restrict__ wlhi, unsigned short* __restrict__ wllo,
                        unsigned short* __restrict__ wrhi, unsigned short* __restrict__ wrlo,
                        unsigned short* __restrict__ wnhi, unsigned short* __restrict__ wnlo,
                        const int* __restrict__ ei, int* __restrict__ deg,
                        const float* __restrict__ Wres, const float* __restrict__ bias_conv,
                        const float* __restrict__ blin,
                        unsigned short* __restrict__ wchi, unsigned short* __restrict__ wclo,
                        float* __restrict__ bcomb)
{
    const int t = threadIdx.x;
    if (blockIdx.x < NCVT) {
        const int NX = N_NODES * IN_CH, NW = HCH * IN_CH;
        const int TOT4 = (NX + 3 * NW) >> 2;
        const int stride = NCVT * 256;
        for (int q = blockIdx.x * 256 + t; q < TOT4; q += stride) {
            int i = q << 2;
            const float* s; unsigned short *hi, *lo; int k;
            if (i < NX)               { s = x;    hi = xhi;  lo = xlo;  k = i; }
            else if (i < NX + NW)     { s = Wl;   hi = wlhi; lo = wllo; k = i - NX; }
            else if (i < NX + 2 * NW) { s = Wr;   hi = wrhi; lo = wrlo; k = i - NX - NW; }
            else                      { s = Wlin; hi = wnhi; lo = wnlo; k = i - NX - 2 * NW; }
            f4v f = *(const f4v*)&s[k];
            u16x4 h, l;
            #pragma unroll
            for (int e = 0; e < 4; ++e) {
                unsigned short hh = bf16_rne(f[e]);
                h[e] = hh;
                l[e] = bf16_rne(f[e] - bf16_to_f(hh));
            }
            *(u16x4*)&hi[k] = h;
            *(u16x4*)&lo[k] = l;
        }
        for (int e = blockIdx.x * 256 + t; e < ETOT; e += stride) {
            int dst = (e < N_EDGES) ? ei[N_EDGES + e] : (e - N_EDGES);
            atomicAdd(&deg[dst], 1);
        }
    } else if (t < 128) {
        // Wcomb = Wlin @ Wres, bcomb = blin + Wlin @ bias_conv
        const int j = blockIdx.x - NCVT;    // 0..127
        float s = 0.0f, pb = 0.0f;
        for (int m = 0; m < HCH; ++m) {
            float wl = Wlin[j * HCH + m];
            s  += wl * Wres[m * IN_CH + t];
            pb += wl * bias_conv[m];
        }
        unsigned short h = bf16_rne(s);
        wchi[j * IN_CH + t] = h;
        wclo[j * IN_CH + t] = bf16_rne(s - bf16_to_f(h));
        if (t == 0) bcomb[j] = blin[j] + pb;
    }
}

// ---- merged projection GEMM, plane-major output (R15-proven: 74 us) ----
__global__ __launch_bounds__(256) void proj_gemm(
    const unsigned short* __restrict__ Ahi,
    const unsigned short* __restrict__ WLhi, const unsigned short* __restrict__ WLlo,
    const unsigned short* __restrict__ WRhi, const unsigned short* __restrict__ WRlo,
    const float* __restrict__ bl, const float* __restrict__ br,
    const float* __restrict__ att,
    unsigned short* __restrict__ xl_h, unsigned short* __restrict__ xr_h,
    float* __restrict__ dl, float* __restrict__ dr, int M)
{
    __shared__ unsigned short cst[128][136];
    const int id  = blockIdx.x;
    const int nat = (id & 7) * (GRID_P / 8) + (id >> 3);   // XCD-contiguous
    const int bx  = nat >> 4;        // row-tile   0..156
    const int by  = nat & 15;        // col-block  0..15
    const int t    = threadIdx.x;
    const int wave = t >> 6, lane = t & 63;
    const int wr = wave >> 1, wc = wave & 1;
    const int l15 = lane & 15, lg = lane >> 4;
    const int m0 = bx * 128 + wr * 64;
    const int sel = by >> 3;
    const int hh  = by & 7;
    const int col0 = hh * 128;
    const unsigned short* Whi = sel ? WRhi : WLhi;
    const unsigned short* Wlo = sel ? WRlo : WLlo;
    const float* bias = sel ? br : bl;
    unsigned short* C = sel ? xr_h : xl_h;
    float* D = sel ? dr : dl;
    const int koff = lg * 8;
    const int K = IN_CH;

    int rowA[4], colB[4];
    #pragma unroll
    for (int i = 0; i < 4; ++i) { int r = m0 + i * 16 + l15; rowA[i] = r < M ? r : M - 1; }
    #pragma unroll
    for (int j = 0; j < 4; ++j) colB[j] = col0 + wc * 64 + j * 16 + l15;

    float bj[4];
    #pragma unroll
    for (int j = 0; j < 4; ++j) bj[j] = bias[colB[j]];

    f4v acc[4][4];
    #pragma unroll
    for (int i = 0; i < 4; ++i)
        #pragma unroll
        for (int j = 0; j < 4; ++j) acc[i][j] = (f4v){0.f, 0.f, 0.f, 0.f};

    for (int k0 = 0; k0 < K; k0 += 32) {
        s8v ah[4], bh[4], blv[4];
        #pragma unroll
        for (int i = 0; i < 4; ++i)
            ah[i] = *(const s8v*)&Ahi[(size_t)rowA[i] * K + k0 + koff];
        #pragma unroll
        for (int j = 0; j < 4; ++j) {
            size_t off = (size_t)colB[j] * K + k0 + koff;
            bh[j]  = *(const s8v*)&Whi[off];
            blv[j] = *(const s8v*)&Wlo[off];
        }
        #pragma unroll
        for (int i = 0; i < 4; ++i)
            #pragma unroll
            for (int j = 0; j < 4; ++j) {
                acc[i][j] = __builtin_amdgcn_mfma_f32_16x16x32_bf16(ah[i], bh[j],  acc[i][j], 0, 0, 0);
                acc[i][j] = __builtin_amdgcn_mfma_f32_16x16x32_bf16(ah[i], blv[j], acc[i][j], 0, 0, 0);
            }
    }

    // stage as bf16 (+bias)
    #pragma unroll
    for (int i = 0; i < 4; ++i)
        #pragma unroll
        for (int r = 0; r < 4; ++r) {
            int lr = wr * 64 + i * 16 + lg * 4 + r;
            #pragma unroll
            for (int j = 0; j < 4; ++j)
                cst[lr][wc * 64 + j * 16 + l15] = bf16_rne(acc[i][j][r] + bj[j]);
        }
    __syncthreads();

    // contiguous plane-major store: 32 KB sequential per block
    {
        const int c8  = (t & 15) * 8;
        const int r16 = t >> 4;
        #pragma unroll
        for (int it = 0; it < 8; ++it) {
            int lr = it * 16 + r16;
            int row = bx * 128 + lr;
            if (row >= M) continue;
            u16x8 v = *(const u16x8*)&cst[lr][c8];
            *(u16x8*)&C[(size_t)hh * PL + (size_t)row * 128 + c8] = v;
        }
    }

    // att-dot per row (this head), plane-major dl/dr
    {
        const int r2  = t >> 1;            // row 0..127
        const int ch0 = (t & 1) * 64;
        float q = 0.0f;
        #pragma unroll
        for (int c = 0; c < 64; c += 8) {
            u16x8 cv = *(const u16x8*)&cst[r2][ch0 + c];
            f4v a0 = *(const f4v*)&att[hh * 128 + ch0 + c];
            f4v a1 = *(const f4v*)&att[hh * 128 + ch0 + c + 4];
            q = fmaf(a0[0], bf16_to_f(cv[0]), q);
            q = fmaf(a0[1], bf16_to_f(cv[1]), q);
            q = fmaf(a0[2], bf16_to_f(cv[2]), q);
            q = fmaf(a0[3], bf16_to_f(cv[3]), q);
            q = fmaf(a1[0], bf16_to_f(cv[4]), q);
            q = fmaf(a1[1], bf16_to_f(cv[5]), q);
            q = fmaf(a1[2], bf16_to_f(cv[6]), q);
            q = fmaf(a1[3], bf16_to_f(cv[7]), q);
        }
        q += __shfl_xor(q, 1, 64);
        int row = bx * 128 + r2;
        if ((t & 1) == 0 && row < M) D[hh * N_NODES + row] = q;
    }
}

// ---- final GEMM + ELU + fused pooling: 32-row tile, 2 waves, 625 blocks ----
__global__ __launch_bounds__(128) void mfma_gemm2(
    const unsigned short* __restrict__ A1h,
    const unsigned short* __restrict__ B1hi, const unsigned short* __restrict__ B1lo, int K1,
    const unsigned short* __restrict__ A2hi, const unsigned short* __restrict__ A2lo,
    const unsigned short* __restrict__ B2hi, const unsigned short* __restrict__ B2lo, int K2,
    const float* __restrict__ bias, const int* __restrict__ batch,
    float* __restrict__ pooled, int M)
{
    __shared__ float cst[32][130];
    __shared__ int batch_s[32];
    const int t    = threadIdx.x;
    const int wc   = t >> 6, lane = t & 63;
    const int l15 = lane & 15, lg = lane >> 4;
    const int m0 = blockIdx.x * 32;
    const int n0 = wc * 64;
    const int koff = lg * 8;

    if (t < 32) {
        int row = m0 + t;
        batch_s[t] = (row < M) ? batch[row] : -1;
    }

    int rowA[2], colB[4];
    #pragma unroll
    for (int i = 0; i < 2; ++i) { int r = m0 + i * 16 + l15; rowA[i] = r < M ? r : M - 1; }
    #pragma unroll
    for (int j = 0; j < 4; ++j) colB[j] = n0 + j * 16 + l15;

    float bj[4];
    #pragma unroll
    for (int j = 0; j < 4; ++j) bj[j] = bias[colB[j]];

    f4v acc[2][4];
    #pragma unroll
    for (int i = 0; i < 2; ++i)
        #pragma unroll
        for (int j = 0; j < 4; ++j) acc[i][j] = (f4v){0.f, 0.f, 0.f, 0.f};

    for (int k0 = 0; k0 < K1; k0 += 32) {
        s8v ah[2], bh[4], blv[4];
        #pragma unroll
        for (int i = 0; i < 2; ++i)
            ah[i] = *(const s8v*)&A1h[(size_t)rowA[i] * K1 + k0 + koff];
        #pragma unroll
        for (int j = 0; j < 4; ++j) {
            size_t off = (size_t)colB[j] * K1 + k0 + koff;
            bh[j]  = *(const s8v*)&B1hi[off];
            blv[j] = *(const s8v*)&B1lo[off];
        }
        #pragma unroll
        for (int i = 0; i < 2; ++i)
            #pragma unroll
            for (int j = 0; j < 4; ++j) {
                acc[i][j] = __builtin_amdgcn_mfma_f32_16x16x32_bf16(ah[i], bh[j],  acc[i][j], 0, 0, 0);
                acc[i][j] = __builtin_amdgcn_mfma_f32_16x16x32_bf16(ah[i], blv[j], acc[i][j], 0, 0, 0);
            }
    }
    for (int k0 = 0; k0 < K2; k0 += 32) {
        s8v ah[2], al[2], bh[4], blv[4];
        #pragma unroll
        for (int i = 0; i < 2; ++i) {
            size_t off = (size_t)rowA[i] * K2 + k0 + koff;
            ah[i] = *(const s8v*)&A2hi[off];
            al[i] = *(const s8v*)&A2lo[off];
        }
        #pragma unroll
        for (int j = 0; j < 4; ++j) {
            size_t off = (size_t)colB[j] * K2 + k0 + koff;
            bh[j]  = *(const s8v*)&B2hi[off];
            blv[j] = *(const s8v*)&B2lo[off];
        }
        #pragma unroll
        for (int i = 0; i < 2; ++i)
            #pragma unroll
            for (int j = 0; j < 4; ++j) {
                acc[i][j] = __builtin_amdgcn_mfma_f32_16x16x32_bf16(ah[i], bh[j],  acc[i][j], 0, 0, 0);
                acc[i][j] = __builtin_amdgcn_mfma_f32_16x16x32_bf16(ah[i], blv[j], acc[i][j], 0, 0, 0);
                acc[i][j] = __builtin_amdgcn_mfma_f32_16x16x32_bf16(al[i], bh[j],  acc[i][j], 0, 0, 0);
            }
    }

    #pragma unroll
    for (int i = 0; i < 2; ++i)
        #pragma unroll
        for (int r = 0; r < 4; ++r) {
            int lr = i * 16 + lg * 4 + r;
            #pragma unroll
            for (int j = 0; j < 4; ++j) {
                float v = acc[i][j][r] + bj[j];
                v = v > 0.0f ? v : expm1f(v);   // ELU
                cst[lr][n0 + j * 16 + l15] = v;
            }
        }
    __syncthreads();

    const int col = t;
    if (col < 128) {
        float run = 0.0f;
        int cur_g = -2;
        #pragma unroll 4
        for (int r = 0; r < 32; ++r) {
            int g = batch_s[r];
            if (g != cur_g) {
                if (cur_g >= 0) atomicAdd(&pooled[cur_g * CPH + col], run);
                run = 0.0f; cur_g = g;
            }
            if (g >= 0) run += cst[r][col];
        }
        if (cur_g >= 0) atomicAdd(&pooled[cur_g * CPH + col], run);
    }
}

// ---- CSR build: single-block scan, 4 elems/thread ----
__global__ __launch_bounds__(256) void scan_kernel(
    const int* __restrict__ deg, int* __restrict__ rowptr, int* __restrict__ wof)
{
    __shared__ int wsum[4];
    __shared__ int carry_s;
    const int t = threadIdx.x, wave = t >> 6, lane = t & 63;
    if (t == 0) { carry_s = 0; rowptr[0] = 0; }
    __syncthreads();
    for (int base = 0; base < N_NODES; base += 1024) {
        int idx = base + t * 4;
        int d[4], p[4];
        #pragma unroll
        for (int k = 0; k < 4; ++k)
            d[k] = (idx + k < N_NODES) ? deg[idx + k] : 0;
        p[0] = d[0]; p[1] = p[0] + d[1]; p[2] = p[1] + d[2]; p[3] = p[2] + d[3];
        int v = p[3];
        #pragma unroll
        for (int off = 1; off < 64; off <<= 1) {
            int u = __shfl_up(v, off, 64);
            if (lane >= off) v += u;
        }
        if (lane == 63) wsum[wave] = v;
        __syncthreads();
        int woff = carry_s;
        #pragma unroll
        for (int w = 0; w < 4; ++w) if (w < wave) woff += wsum[w];
        int tbase = woff + v - p[3];
        #pragma unroll
        for (int k = 0; k < 4; ++k) {
            if (idx + k < N_NODES) {
                rowptr[idx + k + 1] = tbase + p[k];
                wof[idx + k] = tbase + p[k] - d[k];
            }
        }
        __syncthreads();
        if (t == 255) carry_s = woff + v;
        __syncthreads();
    }
}

// ---- CSR build: scatter edge src ids ----
__global__ void scatter_kernel(const int* __restrict__ ei, int* __restrict__ wof,
                               int* __restrict__ csr_src)
{
    for (int e = blockIdx.x * blockDim.x + threadIdx.x; e < ETOT;
         e += gridDim.x * blockDim.x) {
        int src, dst;
        if (e < N_EDGES) { src = ei[e]; dst = ei[N_EDGES + e]; }
        else             { src = dst = e - N_EDGES; }
        int p = atomicAdd(&wof[dst], 1);
        csr_src[p] = src;
    }
}

// ---- fused logits + online softmax + aggregation, head<->XCD affinity ----
// Grid 10000 = 8 heads x 1250 chunks; head = blockIdx&7 pins each head's
// gathers to one XCD whose L2 mostly holds that 5.1-MB plane.
// Block: 256 thr = 16 dsts x 16 lanes (8 ch each). R10-style pairwise
// online softmax (split-merge removed: measured net-negative).
__global__ __launch_bounds__(256) void agg_fused(
    const unsigned short* __restrict__ xl_h, const unsigned short* __restrict__ xr_h,
    const float* __restrict__ att,
    const float* __restrict__ dl, const float* __restrict__ dr,
    const int* __restrict__ rowptr, const int* __restrict__ csr_src,
    unsigned short* __restrict__ agg_h)
{
    const int bid = blockIdx.x;
    const int h     = bid & 7;          // head -> XCD
    const int chunk = bid >> 3;         // 0..1249
    const int t = threadIdx.x;
    const int dg = t >> 4;              // dst within chunk 0..15
    const int l  = t & 15;              // lane within head-group
    const int dst = chunk * 16 + dg;    // 20000 = 1250*16 exact
    const size_t pbase = (size_t)h * PL + l * 8;
    const int beg = rowptr[dst], end = rowptr[dst + 1];

    const u16x8 bh8 = *(const u16x8*)&xr_h[pbase + (size_t)dst * 128];
    f8v b;
    #pragma unroll
    for (int e = 0; e < 8; ++e) b[e] = bf16_to_f(bh8[e]);
    f8v w04;
    {
        f4v a0 = *(const f4v*)&att[h * 128 + l * 8];
        f4v a1 = *(const f4v*)&att[h * 128 + l * 8 + 4];
        #pragma unroll
        for (int e = 0; e < 4; ++e) { w04[e] = 0.4f * a0[e]; w04[e + 4] = 0.4f * a1[e]; }
    }
    const float pb = 0.6f * dr[h * N_NODES + dst];

    float m = -__builtin_inff(), s = 0.0f;
    f8v acc = {0.f, 0.f, 0.f, 0.f, 0.f, 0.f, 0.f, 0.f};

    int j = beg;
    for (; j + 1 < end; j += 2) {
        const int s0 = csr_src[j], s1 = csr_src[j + 1];
        const u16x8 vh0 = *(const u16x8*)&xl_h[pbase + (size_t)s0 * 128];
        const u16x8 vh1 = *(const u16x8*)&xl_h[pbase + (size_t)s1 * 128];
        const float d0 = dl[h * N_NODES + s0], d1 = dl[h * N_NODES + s1];
        f8v v0, v1;
        #pragma unroll
        for (int e = 0; e < 8; ++e) { v0[e] = bf16_to_f(vh0[e]); v1[e] = bf16_to_f(vh1[e]); }

        float q0 = w04[0] * __builtin_fabsf(v0[0] + b[0]);
        float q1 = w04[0] * __builtin_fabsf(v1[0] + b[0]);
        #pragma unroll
        for (int e = 1; e < 8; ++e) {
            q0 = fmaf(w04[e], __builtin_fabsf(v0[e] + b[e]), q0);
            q1 = fmaf(w04[e], __builtin_fabsf(v1[e] + b[e]), q1);
        }
        #pragma unroll
        for (int off = 8; off; off >>= 1) {
            q0 += __shfl_xor(q0, off, 16);
            q1 += __shfl_xor(q1, off, 16);
        }
        const float p0 = fmaf(0.6f, d0, q0) + pb;
        const float p1 = fmaf(0.6f, d1, q1) + pb;

        const float mx = fmaxf(p0, p1);
        if (mx > m) {
            float scale = __expf(m - mx);   // first pair: exp(-inf)=0
            float e0 = __expf(p0 - mx), e1 = __expf(p1 - mx);
            s = s * scale + e0 + e1;
            acc = acc * scale + v0 * e0 + v1 * e1;
            m = mx;
        } else {
            float e0 = __expf(p0 - m), e1 = __expf(p1 - m);
            s += e0 + e1;
            acc += v0 * e0 + v1 * e1;
        }
    }
    if (j < end) {   // tail edge
        const int s0 = csr_src[j];
        const u16x8 vh0 = *(const u16x8*)&xl_h[pbase + (size_t)s0 * 128];
        const float d0 = dl[h * N_NODES + s0];
        f8v v0;
        #pragma unroll
        for (int e = 0; e < 8; ++e) v0[e] = bf16_to_f(vh0[e]);
        float q0 = w04[0] * __builtin_fabsf(v0[0] + b[0]);
        #pragma unroll
        for (int e = 1; e < 8; ++e)
            q0 = fmaf(w04[e], __builtin_fabsf(v0[e] + b[e]), q0);
        #pragma unroll
        for (int off = 8; off; off >>= 1) q0 += __shfl_xor(q0, off, 16);
        const float p0 = fmaf(0.6f, d0, q0) + pb;
        if (p0 > m) {
            float scale = __expf(m - p0);
            s = s * scale + 1.0f;
            acc = acc * scale + v0;
            m = p0;
        } else {
            float e0 = __expf(p0 - m);
            s += e0;
            acc += v0 * e0;
        }
    }

    const float inv = 1.0f / (s + 1e-16f);
    f8v r = acc * inv;
    u16x8 hv;
    #pragma unroll
    for (int e = 0; e < 8; ++e) hv[e] = bf16_rne(r[e]);
    *(u16x8*)&agg_h[(size_t)dst * HCH + h * 128 + l * 8] = hv;
}

// ---- MLP head: one block per graph, parallel dot products ----
__global__ __launch_bounds__(128) void head_kernel(
    const float* __restrict__ pooled, const int* __restrict__ batch,
    const float* __restrict__ W1, const float* __restrict__ b1,
    const float* __restrict__ W2, const float* __restrict__ b2,
    const float* __restrict__ W3, const float* __restrict__ b3,
    float* __restrict__ out)
{
    __shared__ float sm_pool[128];
    __shared__ float sm_y1[16];
    __shared__ float sm_y2[32];
    const int g = blockIdx.x;
    const int t = threadIdx.x;

    int lo = 0, hi = N_NODES;
    while (lo < hi) { int mid = (lo + hi) >> 1; if (batch[mid] <  g) lo = mid + 1; else hi = mid; }
    const int s0 = lo;
    hi = N_NODES;
    while (lo < hi) { int mid = (lo + hi) >> 1; if (batch[mid] <= g) lo = mid + 1; else hi = mid; }
    const float inv = 1.0f / fmaxf((float)(lo - s0), 1.0f);

    sm_pool[t] = pooled[g * CPH + t] * inv;
    __syncthreads();

    {
        const int j  = t >> 3;
        const int c0 = (t & 7) * 16;
        float s = 0.0f;
        #pragma unroll
        for (int k = 0; k < 16; k += 4) {
            f4v wv = *(const f4v*)&W1[j * CPH + c0 + k];
            f4v pv = *(const f4v*)&sm_pool[c0 + k];
            s = fmaf(wv[0], pv[0], s); s = fmaf(wv[1], pv[1], s);
            s = fmaf(wv[2], pv[2], s); s = fmaf(wv[3], pv[3], s);
        }
        s += __shfl_xor(s, 1, 8);
        s += __shfl_xor(s, 2, 8);
        s += __shfl_xor(s, 4, 8);
        if ((t & 7) == 0) sm_y1[j] = fmaxf(s + b1[j], 0.0f);
    }
    __syncthreads();

    if (t < 32) {
        float s = b2[t];
        #pragma unroll
        for (int k = 0; k < 16; ++k) s = fmaf(W2[t * 16 + k], sm_y1[k], s);
        sm_y2[t] = fmaxf(s, 0.0f);
    }
    __syncthreads();

    if (t < 5) {
        float s = b3[t];
        #pragma unroll
        for (int k = 0; k < 32; ++k) s = fmaf(W3[t * 32 + k], sm_y2[k], s);
        out[g * 5 + t] = s;
    }
}

extern "C" void kernel_launch(void* const* d_in, const int* in_sizes, int n_in,
                              void* d_out, int out_size, void* d_ws, size_t ws_size,
                              hipStream_t stream)
{
    const float* x         = (const float*)d_in[0];
    const int*   ei        = (const int*)  d_in[1];
    const int*   batch     = (const int*)  d_in[2];
    const float* Wl        = (const float*)d_in[3];
    const float* bl        = (const float*)d_in[4];
    const float* Wr        = (const float*)d_in[5];
    const float* br        = (const float*)d_in[6];
    const float* att       = (const float*)d_in[7];
    const float* Wres      = (const float*)d_in[8];
    const float* bias_conv = (const float*)d_in[9];
    const float* Wlin      = (const float*)d_in[10];
    const float* blin      = (const float*)d_in[11];
    const float* W1        = (const float*)d_in[12];
    const float* b1        = (const float*)d_in[13];
    const float* W2        = (const float*)d_in[14];
    const float* b2        = (const float*)d_in[15];
    const float* W3        = (const float*)d_in[16];
    const float* b3        = (const float*)d_in[17];
    float* out = (float*)d_out;

    // ---- workspace layout (~139 MB) ----
    unsigned short* xl_h  = (unsigned short*)d_ws;              // [8][N][128] u16 41 MB
    unsigned short* xr_h  = xl_h + (size_t)N_NODES * HCH;       // [8][N][128] u16 41 MB
    unsigned short* agg_h = xr_h + (size_t)N_NODES * HCH;       // [N][1024] u16 41 MB
    float* pooled = (float*)(agg_h + (size_t)N_NODES * HCH);    // NG*CPH f
    float* bcomb  = pooled + NG * CPH;                          // 128 f
    float* dl     = bcomb + 128;                                // [8][N] f
    float* dr     = dl + (size_t)N_NODES * 8;                   // [8][N] f
    unsigned short* x_hi  = (unsigned short*)(dr + (size_t)N_NODES * 8);
    unsigned short* x_lo  = x_hi  + (size_t)N_NODES * IN_CH;
    unsigned short* wl_hi = x_lo  + (size_t)N_NODES * IN_CH;
    unsigned short* wl_lo = wl_hi + HCH * IN_CH;
    unsigned short* wr_hi = wl_lo + HCH * IN_CH;
    unsigned short* wr_lo = wr_hi + HCH * IN_CH;
    unsigned short* wn_hi = wr_lo + HCH * IN_CH;
    unsigned short* wn_lo = wn_hi + CPH * HCH;
    unsigned short* wc_hi = wn_lo + CPH * HCH;
    unsigned short* wc_lo = wc_hi + CPH * IN_CH;
    int* deg     = (int*)(wc_lo + CPH * IN_CH);                 // N
    int* rowptr  = deg + N_NODES;                               // N+1
    int* wof     = rowptr + N_NODES + 1;                        // N
    int* csr_src = wof + N_NODES;                               // ETOT

    init_kernel<<<(N_NODES + 255) / 256, 256, 0, stream>>>(deg, pooled);

    cvt_all<<<NCVT + 128, 256, 0, stream>>>(x, Wl, Wr, Wlin,
                                            x_hi, x_lo, wl_hi, wl_lo,
                                            wr_hi, wr_lo, wn_hi, wn_lo,
                                            ei, deg,
                                            Wres, bias_conv, blin,
                                            wc_hi, wc_lo, bcomb);

    proj_gemm<<<GRID_P, 256, 0, stream>>>(x_hi, wl_hi, wl_lo, wr_hi, wr_lo,
                                          bl, br, att, xl_h, xr_h, dl, dr, N_NODES);

    scan_kernel<<<1, 256, 0, stream>>>(deg, rowptr, wof);
    scatter_kernel<<<1024, 256, 0, stream>>>(ei, wof, csr_src);

    agg_fused<<<HEADS * (N_NODES / 16), 256, 0, stream>>>(xl_h, xr_h, att, dl, dr,
                                                          rowptr, csr_src, agg_h);

    dim3 g2((N_NODES + 31) / 32, 1);
    mfma_gemm2<<<g2, 128, 0, stream>>>(agg_h, wn_hi, wn_lo, HCH,
                                       x_hi, x_lo, wc_hi, wc_lo, IN_CH,
                                       bcomb, batch, pooled, N_NODES);

    head_kernel<<<NG, 128, 0, stream>>>(pooled, batch, W1, b1, W2, b2, W3, b3, out);
}